// Round 12
// baseline (98.005 us; speedup 1.0000x reference)
//
#include <hip/hip_runtime.h>
#include <math.h>

// ---------- constants (normalization folded per the reference) ----------
#define SQ15f      3.8729833462074170f   // sqrt(15)
#define C2_XZ      1.7320508075688772f   // sqrt(3)
#define C2_ZX      0.8660254037844386f   // sqrt(3)/2
#define C3_A       0.4082482904638631f   // 1/sqrt(6)
#define C3_B       0.6123724356957945f   // sqrt(24)/8
#define EMB_SCALE  2.8234622000789103f   // sqrt(10)/1.12

typedef float v2f __attribute__((ext_vector_type(2)));
typedef float v4f __attribute__((ext_vector_type(4)));

// lgkm-only barrier: orders LDS + syncs the block WITHOUT draining vmcnt,
// so in-flight nontemporal stores keep retiring through the next phase.
__device__ __forceinline__ void lds_barrier() {
    asm volatile("s_waitcnt lgkmcnt(0)\n\ts_barrier" ::: "memory");
    __builtin_amdgcn_sched_barrier(0);
}

// Shared buffer (two-pass): logical index g lives at buf[g + (g>>4)]
// (pad-every-16: conflict-free stride-17 row writes AND stride-4 v4f reads).
//   pass 1: sh  (g in [0,4096), max addr 4350)
//   pass 2: emb (g in [0,2560), max addr 2718)
#define BUFSZ 4352   // floats = 17.4 KB -> 9 blocks/CU by LDS

__global__ __launch_bounds__(256, 8)
void fused_kernel(const float* __restrict__ pos,
                  const float* __restrict__ qpos,
                  const float* __restrict__ feat,
                  const int*   __restrict__ esrc,
                  const int*   __restrict__ edst,
                  float* __restrict__ out,
                  int E, int nblk_edge, int n2feat,
                  unsigned long long OFF_SRC, unsigned long long OFF_DST,
                  unsigned long long OFF_EMB, unsigned long long OFF_SH,
                  unsigned long long OFF_LEN) {
    const int tid = threadIdx.x;
    const int blk = blockIdx.x;

    if (blk >= nblk_edge) {                 // ---- feature passthrough blocks ----
        int i = (blk - nblk_edge) * 256 + tid;
        if (i == 0) { out[0] = 10.0f; out[1] = 1000.0f; }   // Nt, Ny
        if (i < n2feat) {
            v2f v = __builtin_nontemporal_load(((const v2f*)feat) + i);
            __builtin_nontemporal_store(v, ((v2f*)(out + 2)) + i);
        }
        return;
    }

    __shared__ float buf[BUFSZ];

    const int base = blk * 256;
    const int nb   = min(256, E - base);
    const long long e = base + tid;

    if (nb == 256) {
        // ================= full block: two-pass LDS staging =================
        // ---- front: indices, gather, basic geometry ----
        int s = __builtin_nontemporal_load(esrc + e);
        int d = __builtin_nontemporal_load(edst + e);

        float vx = qpos[3 * s + 0] - pos[3 * d + 0];
        float vy = qpos[3 * s + 1] - pos[3 * d + 1];
        float vz = qpos[3 * s + 2] - pos[3 * d + 2];

        float ss  = vx * vx + vy * vy + vz * vz;
        float len = sqrtf(ss + 1e-8f);

        float n   = sqrtf(ss);
        float inv = 1.0f / fmaxf(n, 1e-12f);
        float x = vx * inv, y = vy * inv, z = vz * inv;

        __builtin_nontemporal_store((float)s, out + OFF_SRC + e);
        __builtin_nontemporal_store((float)d, out + OFF_DST + e);
        __builtin_nontemporal_store(len,      out + OFF_LEN + e);

        // ---- pass 1: compute sh straight into LDS (regs die immediately) ----
        {
            float x2 = x * x, y2 = y * y, z2 = z * z;
            float x2z2 = x2 + z2;
            float s20 = SQ15f * x * z;
            float s24 = 0.5f * SQ15f * (z2 - x2);
            float q   = 4.0f * y2 - x2z2;

            float* shp = &buf[tid * 17];          // == g+(g>>4) for g=tid*16+c
            shp[0] = 1.0f;
            shp[1] = x;  shp[2] = y;  shp[3] = z;
            shp[4] = C2_XZ * x * z;
            shp[5] = C2_XZ * x * y;
            shp[6] = y2 - 0.5f * x2z2;
            shp[7] = C2_XZ * y * z;
            shp[8] = C2_ZX * (z2 - x2);
            shp[9]  = C3_A * (s20 * z + s24 * x);
            shp[10] = s20 * y;
            shp[11] = C3_B * q * x;
            shp[12] = 0.5f * y * (2.0f * y2 - 3.0f * x2z2);
            shp[13] = C3_B * z * q;
            shp[14] = s24 * y;
            shp[15] = C3_A * (s24 * z - s20 * x);
        }
        lds_barrier();

        // ---- bulk-store sh: 4096 floats, span starts ≡2 (mod 4) ----
        float* sgb = out + OFF_SH + 16ULL * (unsigned long long)base;
#pragma unroll
        for (int i = 0; i < 4; ++i) {
            int idx = i * 256 + tid;
            if (idx < 1023) {
                int g0 = 2 + 4 * idx;
                v4f v = { buf[g0 + (g0 >> 4)],
                          buf[(g0 + 1) + ((g0 + 1) >> 4)],
                          buf[(g0 + 2) + ((g0 + 2) >> 4)],
                          buf[(g0 + 3) + ((g0 + 3) >> 4)] };
                __builtin_nontemporal_store(v, (v4f*)(sgb + g0));
            }
        }
        if (tid == 0) { v2f h = { buf[0], buf[1] };           __builtin_nontemporal_store(h, (v2f*)sgb); }
        if (tid == 1) { v2f t = { buf[4094 + (4094 >> 4)], buf[4095 + (4095 >> 4)] };
                        __builtin_nontemporal_store(t, (v2f*)(sgb + 4094)); }

        lds_barrier();   // all sh reads done -> buffer reusable

        // ---- pass 2: compute emb straight into LDS ----
        {
            float t = (0.2f - len) * 5.5f;
            float cut;
            if (t <= 0.0f)      cut = 1.0f;
            else if (t >= 1.0f) cut = 0.0f;
            else {
                float t2 = t * t;
                float t4 = t2 * t2;
                cut = 1.0f - (5.0f * t4 - 4.0f * t4 * t);
            }
            float cs = cut * EMB_SCALE;
#pragma unroll
            for (int j = 0; j < 10; ++j) {
                float m  = (9.0f + 8.0f * (float)j) * (1.0f / 81.0f);
                float dd = (len - m) * 9.0f;
                int p = tid * 10 + j;
                buf[p + (p >> 4)] = __expf(-dd * dd) * cs;
            }
        }
        lds_barrier();

        // ---- bulk-store emb: 2560 floats, span starts ≡2 (mod 4) ----
        float* egb = out + OFF_EMB + 10ULL * (unsigned long long)base;
#pragma unroll
        for (int i = 0; i < 3; ++i) {
            int idx = i * 256 + tid;
            if (idx < 639) {
                int p0 = 2 + 4 * idx;
                v4f v = { buf[p0 + (p0 >> 4)],
                          buf[(p0 + 1) + ((p0 + 1) >> 4)],
                          buf[(p0 + 2) + ((p0 + 2) >> 4)],
                          buf[(p0 + 3) + ((p0 + 3) >> 4)] };
                __builtin_nontemporal_store(v, (v4f*)(egb + p0));
            }
        }
        if (tid == 0) { v2f h = { buf[0], buf[1] };           __builtin_nontemporal_store(h, (v2f*)egb); }
        if (tid == 1) { v2f t = { buf[2558 + (2558 >> 4)], buf[2559 + (2559 >> 4)] };
                        __builtin_nontemporal_store(t, (v2f*)(egb + 2558)); }
    } else if (tid < nb) {
        // ================= tail block: direct per-lane stores =================
        int s = __builtin_nontemporal_load(esrc + e);
        int d = __builtin_nontemporal_load(edst + e);

        float vx = qpos[3 * s + 0] - pos[3 * d + 0];
        float vy = qpos[3 * s + 1] - pos[3 * d + 1];
        float vz = qpos[3 * s + 2] - pos[3 * d + 2];

        float ss  = vx * vx + vy * vy + vz * vz;
        float len = sqrtf(ss + 1e-8f);

        float n   = sqrtf(ss);
        float inv = 1.0f / fmaxf(n, 1e-12f);
        float x = vx * inv, y = vy * inv, z = vz * inv;

        float x2 = x * x, y2 = y * y, z2 = z * z;
        float x2z2 = x2 + z2;
        float s20 = SQ15f * x * z;
        float s24 = 0.5f * SQ15f * (z2 - x2);
        float q   = 4.0f * y2 - x2z2;

        float* gs = out + OFF_SH + 16ULL * (unsigned long long)e;
        __builtin_nontemporal_store(1.0f, gs + 0);
        __builtin_nontemporal_store(x, gs + 1);
        __builtin_nontemporal_store(y, gs + 2);
        __builtin_nontemporal_store(z, gs + 3);
        __builtin_nontemporal_store(C2_XZ * x * z, gs + 4);
        __builtin_nontemporal_store(C2_XZ * x * y, gs + 5);
        __builtin_nontemporal_store(y2 - 0.5f * x2z2, gs + 6);
        __builtin_nontemporal_store(C2_XZ * y * z, gs + 7);
        __builtin_nontemporal_store(C2_ZX * (z2 - x2), gs + 8);
        __builtin_nontemporal_store(C3_A * (s20 * z + s24 * x), gs + 9);
        __builtin_nontemporal_store(s20 * y, gs + 10);
        __builtin_nontemporal_store(C3_B * q * x, gs + 11);
        __builtin_nontemporal_store(0.5f * y * (2.0f * y2 - 3.0f * x2z2), gs + 12);
        __builtin_nontemporal_store(C3_B * z * q, gs + 13);
        __builtin_nontemporal_store(s24 * y, gs + 14);
        __builtin_nontemporal_store(C3_A * (s24 * z - s20 * x), gs + 15);

        float t = (0.2f - len) * 5.5f;
        float cut;
        if (t <= 0.0f)      cut = 1.0f;
        else if (t >= 1.0f) cut = 0.0f;
        else {
            float t2 = t * t;
            float t4 = t2 * t2;
            cut = 1.0f - (5.0f * t4 - 4.0f * t4 * t);
        }
        float cs = cut * EMB_SCALE;

        float* ge = out + OFF_EMB + 10ULL * (unsigned long long)e;
#pragma unroll
        for (int j = 0; j < 10; ++j) {
            float m  = (9.0f + 8.0f * (float)j) * (1.0f / 81.0f);
            float dd = (len - m) * 9.0f;
            __builtin_nontemporal_store(__expf(-dd * dd) * cs, ge + j);
        }

        __builtin_nontemporal_store((float)s, out + OFF_SRC + e);
        __builtin_nontemporal_store((float)d, out + OFF_DST + e);
        __builtin_nontemporal_store(len,      out + OFF_LEN + e);
    }
}

extern "C" void kernel_launch(void* const* d_in, const int* in_sizes, int n_in,
                              void* d_out, int out_size, void* d_ws, size_t ws_size,
                              hipStream_t stream) {
    const float* pos  = (const float*)d_in[0];
    const float* qpos = (const float*)d_in[1];
    const float* feat = (const float*)d_in[2];
    const int*   esrc = (const int*)d_in[3];
    const int*   edst = (const int*)d_in[4];
    float* out = (float*)d_out;

    const int Ftot = in_sizes[2];   // 320000
    const int E    = in_sizes[3];   // 3000000

    const unsigned long long OFF_FEAT = 2;
    const unsigned long long OFF_SRC  = OFF_FEAT + (unsigned long long)Ftot;
    const unsigned long long OFF_DST  = OFF_SRC + (unsigned long long)E;
    const unsigned long long OFF_EMB  = OFF_DST + (unsigned long long)E;
    const unsigned long long OFF_SH   = OFF_EMB + 10ULL * E;
    const unsigned long long OFF_LEN  = OFF_SH  + 16ULL * E;

    const int n2feat    = Ftot / 2;
    const int nblk_edge = (E + 255) / 256;
    const int nblk_feat = (n2feat + 255) / 256;

    fused_kernel<<<nblk_edge + nblk_feat, 256, 0, stream>>>(
        pos, qpos, feat, esrc, edst, out,
        E, nblk_edge, n2feat, OFF_SRC, OFF_DST, OFF_EMB, OFF_SH, OFF_LEN);
}